// Round 1
// baseline (226.937 us; speedup 1.0000x reference)
//
#include <hip/hip_runtime.h>
#include <math.h>

#define FH 256
#define FW 256
#define HW (FH * FW)          // 65536
#define BATCH 16
#define NTGT 256
#define NCH 32
#define EPS_ 1e-7f

__device__ __forceinline__ float sigmoidf_(float x) {
    return 1.0f / (1.0f + expf(-x));
}
__device__ __forceinline__ float softplusf_(float x) {
    // log(1+exp(x)) = max(x,0) + log1p(exp(-|x|))
    return fmaxf(x, 0.0f) + log1pf(expf(-fabsf(x)));
}

// ---------------- init: clear mask (float 0) and win (-1), vectorized ------
__global__ __launch_bounds__(256) void init_kernel(float4* __restrict__ mask4,
                                                   int4* __restrict__ win4) {
    int i = blockIdx.x * 256 + threadIdx.x;
    if (i < BATCH * HW / 4) {
        mask4[i] = make_float4(0.0f, 0.0f, 0.0f, 0.0f);
        win4[i] = make_int4(-1, -1, -1, -1);
    }
}

// ---------------- scatter: assignment priorities + gaussian splat ----------
__global__ __launch_bounds__(256) void scatter_kernel(const float* __restrict__ targets,
                                                      float* __restrict__ mask,
                                                      int* __restrict__ win) {
    int n = blockIdx.x;  // one block per target
    float bif = targets[n * 6 + 0];
    float cx  = targets[n * 6 + 1];
    float cy  = targets[n * 6 + 2];
    float w   = targets[n * 6 + 3];
    float h   = targets[n * 6 + 4];
    int bi = (int)bif;

    if (threadIdx.x == 0) {
        int gi = (int)(cx * (float)FW);
        int gj = (int)(cy * (float)FH);
#pragma unroll
        for (int k = 0; k < 9; ++k) {
            int dxv = k / 3 - 1;   // -1,-1,-1,0,0,0,1,1,1
            int dyv = k % 3 - 1;   // -1,0,1,-1,0,1,-1,0,1
            int nx = gi + dxv, ny = gj + dyv;
            bool inb = (nx >= 0) && (nx < FW) && (ny >= 0) && (ny < FH);
            float ccx = ((float)nx + 0.5f) / (float)FW;
            float ccy = ((float)ny + 0.5f) / (float)FH;
            bool inside = (fabsf(ccx - cx) <= w * 0.5f) && (fabsf(ccy - cy) <= h * 0.5f);
            if (inb && inside) {
                atomicMax(&win[bi * HW + ny * FW + nx], n * 10 + k);
            }
        }
        int cell = min(gj, FH - 1) * FW + min(gi, FW - 1);
        atomicMax(&win[bi * HW + cell], n * 10 + 9);
    }

    // Gaussian splat: exp(-d2/(2*sigma^2)), sigma=1.5 -> /4.5.
    // Radius 12: corner value exp(-144/4.5)=e^-32 ~ 1.2e-14, negligible.
    float tx = cx * (float)FW;
    float ty = cy * (float)FH;
    int itx = (int)tx, ity = (int)ty;
    int x0 = max(0, itx - 12), x1 = min(FW - 1, itx + 12);
    int y0 = max(0, ity - 12), y1 = min(FH - 1, ity + 12);
    int nxw = x1 - x0 + 1;
    int tot = nxw * (y1 - y0 + 1);
    unsigned int* mrow = (unsigned int*)(mask + bi * HW);
    for (int i = threadIdx.x; i < tot; i += blockDim.x) {
        int xx = x0 + i % nxw;
        int yy = y0 + i / nxw;
        float ddx = (float)xx - tx;
        float ddy = (float)yy - ty;
        float g = expf(-(ddx * ddx + ddy * ddy) / 4.5f);
        // non-negative floats: uint bit pattern is order-preserving
        atomicMax(&mrow[yy * FW + xx], __float_as_uint(g));
    }
}

// ---------------- main fused loss kernel: 4 cells per thread, float4 loads --
__global__ __launch_bounds__(256) void main_kernel(const float* __restrict__ raw,
                                                   const float* __restrict__ sal,
                                                   const float* __restrict__ targets,
                                                   const float* __restrict__ mask,
                                                   const int* __restrict__ win,
                                                   float* __restrict__ partials) {
    int tid = blockIdx.x * 256 + threadIdx.x;  // tid in [0, B*HW/4)
    int p0 = tid << 2;                          // first of 4 consecutive cells
    int b = p0 >> 16;                           // HW = 65536, p0..p0+3 same b
    int hw0 = p0 & (HW - 1);

    // ---- attention channel sum: 32 x float4 (16B/lane, fully coalesced) ----
    const float* sp = sal + (size_t)b * NCH * HW + hw0;
    float4 ss = make_float4(0.0f, 0.0f, 0.0f, 0.0f);
#pragma unroll
    for (int c = 0; c < NCH; ++c) {
        float4 v = *reinterpret_cast<const float4*>(sp + (size_t)c * HW);
        ss.x += v.x; ss.y += v.y; ss.z += v.z; ss.w += v.w;
    }
    float4 mk = *reinterpret_cast<const float4*>(mask + p0);
    int4 wv4 = *reinterpret_cast<const int4*>(win + p0);

    // ---- raw: 4 cells * 7 floats = 28 floats = 7 aligned float4 loads ----
    // byte offset = p0*28 = tid*112, and 112 % 16 == 0 -> 16B aligned.
    float rr[28];
    const float4* rp = reinterpret_cast<const float4*>(raw + (size_t)p0 * 7);
#pragma unroll
    for (int q = 0; q < 7; ++q) reinterpret_cast<float4*>(rr)[q] = rp[q];

    float smv[4] = {ss.x, ss.y, ss.z, ss.w};
    float mkv[4] = {mk.x, mk.y, mk.z, mk.w};
    int wvv[4] = {wv4.x, wv4.y, wv4.z, wv4.w};

    float attn_t = 0.0f, conf_t = 0.0f, ciou_t = 0.0f, cls_t = 0.0f, posf = 0.0f;
    int xb = hw0 & (FW - 1);   // hw0 % 4 == 0, so xb+k never carries into y
    int y = hw0 >> 8;
    float fy = (float)y;

#pragma unroll
    for (int k = 0; k < 4; ++k) {
        // attention MSE term
        float smean = smv[k] * (1.0f / 32.0f);
        float dm = smean - mkv[k];
        attn_t += dm * dm;

        const float* r = rr + k * 7;
        float r0 = r[0], r1 = r[1], r2 = r[2], r3 = r[3];
        float z = r[4], l0 = r[5], l1 = r[6];

        float pcx = (sigmoidf_(r0) + (float)(xb + k)) / (float)FW;
        float pcy = (sigmoidf_(r1) + fy) / (float)FH;
        float pw = expf(fminf(fmaxf(r2, -4.0f), 4.0f)) / (float)FW;
        float ph = expf(fminf(fmaxf(r3, -4.0f), 4.0f)) / (float)FH;
        float conf = sigmoidf_(z);

        int wv = wvv[k];
        if (wv >= 0) {
            posf += 1.0f;
            float omc = 1.0f - conf;
            conf_t += 0.25f * omc * omc * softplusf_(-z);

            int t = wv / 10;
            float tcx = targets[t * 6 + 1], tcy = targets[t * 6 + 2];
            float tw = targets[t * 6 + 3], th = targets[t * 6 + 4];
            int cls = (int)targets[t * 6 + 5];

            // CIoU
            float px1 = pcx - pw * 0.5f, py1 = pcy - ph * 0.5f;
            float px2 = pcx + pw * 0.5f, py2 = pcy + ph * 0.5f;
            float tx1 = tcx - tw * 0.5f, ty1 = tcy - th * 0.5f;
            float tx2 = tcx + tw * 0.5f, ty2 = tcy + th * 0.5f;
            float iw = fmaxf(fminf(px2, tx2) - fmaxf(px1, tx1), 0.0f);
            float ih = fmaxf(fminf(py2, ty2) - fmaxf(py1, ty1), 0.0f);
            float inter = iw * ih;
            float uni = pw * ph + tw * th - inter;
            float iou = inter / (uni + EPS_);
            float cw = fmaxf(px2, tx2) - fminf(px1, tx1);
            float chh = fmaxf(py2, ty2) - fminf(py1, ty1);
            float c2 = cw * cw + chh * chh + EPS_;
            float dcx = pcx - tcx, dcy = pcy - tcy;
            float d2 = dcx * dcx + dcy * dcy;
            float dv = atanf(tw / (th + EPS_)) - atanf(pw / (ph + EPS_));
            float v = (4.0f / (float)(M_PI * M_PI)) * dv * dv;
            float alpha = v / (1.0f - iou + v + EPS_);
            ciou_t += 1.0f - iou + d2 / c2 + alpha * v;

            // class NLL (2 classes)
            float m_ = fmaxf(l0, l1);
            float lse = m_ + logf(expf(l0 - m_) + expf(l1 - m_));
            cls_t += lse - ((cls == 0) ? l0 : l1);
        } else {
            conf_t += 0.75f * conf * conf * softplusf_(z);
        }
    }

    // ---- block reduction of 5 sums ----
    float vals[5] = {attn_t, conf_t, ciou_t, cls_t, posf};
#pragma unroll
    for (int j = 0; j < 5; ++j) {
        float v = vals[j];
#pragma unroll
        for (int o = 32; o > 0; o >>= 1) v += __shfl_down(v, o, 64);
        vals[j] = v;
    }
    __shared__ float red[4][5];
    int lane = threadIdx.x & 63;
    int wid = threadIdx.x >> 6;
    if (lane == 0) {
#pragma unroll
        for (int j = 0; j < 5; ++j) red[wid][j] = vals[j];
    }
    __syncthreads();
    if (threadIdx.x == 0) {
#pragma unroll
        for (int j = 0; j < 5; ++j) {
            partials[blockIdx.x * 5 + j] = red[0][j] + red[1][j] + red[2][j] + red[3][j];
        }
    }
}

// ---------------- finalize: reduce partials, combine loss ----------------
__global__ __launch_bounds__(256) void finalize_kernel(const float* __restrict__ partials,
                                                       int nblk, float* __restrict__ out) {
    __shared__ double red[256][5];
    double acc[5] = {0, 0, 0, 0, 0};
    for (int i = threadIdx.x; i < nblk; i += 256) {
#pragma unroll
        for (int j = 0; j < 5; ++j) acc[j] += (double)partials[i * 5 + j];
    }
#pragma unroll
    for (int j = 0; j < 5; ++j) red[threadIdx.x][j] = acc[j];
    __syncthreads();
    for (int s = 128; s > 0; s >>= 1) {
        if (threadIdx.x < s) {
#pragma unroll
            for (int j = 0; j < 5; ++j) red[threadIdx.x][j] += red[threadIdx.x + s][j];
        }
        __syncthreads();
    }
    if (threadIdx.x == 0) {
        double attn = red[0][0];
        double conf = red[0][1];
        double ciou = red[0][2];
        double cls = red[0][3];
        double npos = red[0][4];
        double norm = fmax(npos, 1.0);
        double loss = 2.0 * ciou / norm + 1.0 * conf / norm + 1.0 * cls / norm +
                      5.0 * (attn / (double)(BATCH * HW));
        out[0] = (float)loss;
    }
}

extern "C" void kernel_launch(void* const* d_in, const int* in_sizes, int n_in,
                              void* d_out, int out_size, void* d_ws, size_t ws_size,
                              hipStream_t stream) {
    const float* raw = (const float*)d_in[0];      // (16, 65536, 7)
    const float* sal = (const float*)d_in[1];      // (16, 32, 256, 256)
    const float* targets = (const float*)d_in[2];  // (256, 6)
    float* out = (float*)d_out;

    char* ws = (char*)d_ws;
    float* mask = (float*)ws;                                   // 4 MB
    int* win = (int*)(ws + (size_t)BATCH * HW * sizeof(float)); // 4 MB
    float* partials = (float*)(ws + (size_t)BATCH * HW * 8);    // 1024*5 floats

    const int NBLK4 = (BATCH * HW) / (256 * 4);  // 1024 (init + main, 4 cells/thread)

    init_kernel<<<NBLK4, 256, 0, stream>>>((float4*)mask, (int4*)win);
    scatter_kernel<<<NTGT, 256, 0, stream>>>(targets, mask, win);
    main_kernel<<<NBLK4, 256, 0, stream>>>(raw, sal, targets, mask, win, partials);
    finalize_kernel<<<1, 256, 0, stream>>>(partials, NBLK4, out);
}

// Round 2
// 221.158 us; speedup vs baseline: 1.0261x; 1.0261x over previous
//
#include <hip/hip_runtime.h>
#include <math.h>

#define FH 256
#define FW 256
#define HW (FH * FW)          // 65536
#define BATCH 16
#define NTGT 256
#define NCH 32
#define EPS_ 1e-7f

__device__ __forceinline__ float sigmoidf_(float x) {
    return 1.0f / (1.0f + expf(-x));
}
__device__ __forceinline__ float softplusf_(float x) {
    // log(1+exp(x)) = max(x,0) + log1p(exp(-|x|))
    return fmaxf(x, 0.0f) + log1pf(expf(-fabsf(x)));
}

// ---------------- fused main kernel ----------------
// One block = 1024 consecutive cells = 4 full rows of one batch image.
// The block filters the 256 targets down to the few whose assignment
// neighborhood or Gaussian footprint touches these 4 rows, then each
// thread resolves its 4 cells (win priority max + gaussian max) in
// registers — no mask/win workspace, no init/scatter kernels.
__global__ __launch_bounds__(256) void main_kernel(const float* __restrict__ raw,
                                                   const float* __restrict__ sal,
                                                   const float* __restrict__ targets,
                                                   float* __restrict__ partials) {
    // LDS target list (filtered for this block's batch + row window)
    __shared__ float lcx[NTGT], lcy[NTGT], lw[NTGT], lh[NTGT], ltx[NTGT], lty[NTGT];
    __shared__ int lgi[NTGT], lgj[NTGT], ln[NTGT];
    __shared__ int cnt;

    int b = blockIdx.x >> 6;                 // 64 blocks per batch image
    int y0 = (blockIdx.x & 63) << 2;         // first of 4 rows

    if (threadIdx.x == 0) cnt = 0;
    __syncthreads();

    {   // each thread screens one target
        int n = threadIdx.x;
        float bif = targets[n * 6 + 0];
        float cx = targets[n * 6 + 1];
        float cy = targets[n * 6 + 2];
        float w = targets[n * 6 + 3];
        float h = targets[n * 6 + 4];
        if ((int)bif == b) {
            float tx = cx * (float)FW;
            float ty = cy * (float)FH;
            int gi = (int)tx;
            int gj = (int)ty;
            int gjc = min(gj, FH - 1);
            // win 3x3 neighborhood touches rows [gj-1, gj+1];
            // clamp-candidate touches row gjc; gaussian radius ~<18.
            bool keep = (gj >= y0 - 1 && gj <= y0 + 4) ||
                        (gjc >= y0 && gjc <= y0 + 3) ||
                        (ty >= (float)(y0 - 18) && ty <= (float)(y0 + 21));
            if (keep) {
                int idx = atomicAdd(&cnt, 1);
                lcx[idx] = cx; lcy[idx] = cy; lw[idx] = w; lh[idx] = h;
                ltx[idx] = tx; lty[idx] = ty;
                lgi[idx] = gi; lgj[idx] = gj; ln[idx] = n;
            }
        }
    }
    __syncthreads();
    int tcnt = cnt;

    int tid = blockIdx.x * 256 + threadIdx.x;
    int p0 = tid << 2;                        // first of 4 consecutive cells
    int hw0 = p0 & (HW - 1);
    int xb = hw0 & (FW - 1);
    int y = hw0 >> 8;                         // == y0 + (threadIdx.x>>6)
    float fy = (float)y;

    // ---- per-cell win priority + gaussian max from the LDS list ----
    int wvv[4] = {-1, -1, -1, -1};
    float gm[4] = {0.0f, 0.0f, 0.0f, 0.0f};
    for (int j = 0; j < tcnt; ++j) {
        float cx = lcx[j], cy = lcy[j], w = lw[j], h = lh[j];
        float tx = ltx[j], ty = lty[j];
        int gi = lgi[j], gj = lgj[j], n = ln[j];
        int dyi = y - gj;
        bool yn = (dyi >= -1 && dyi <= 1);
        float ccy = (fy + 0.5f) / (float)FH;
        bool yin = fabsf(ccy - cy) <= h * 0.5f;
        bool yc = (y == min(gj, FH - 1));
        int gic = min(gi, FW - 1);
        float ddy = fy - ty;
        float ddy2 = ddy * ddy;
        int base = n * 10;
#pragma unroll
        for (int k = 0; k < 4; ++k) {
            int x = xb + k;
            // 3x3 neighborhood candidate
            int dxi = x - gi;
            if (yn && yin && dxi >= -1 && dxi <= 1) {
                float ccx = ((float)x + 0.5f) / (float)FW;
                if (fabsf(ccx - cx) <= w * 0.5f) {
                    int prio = base + (dxi + 1) * 3 + (dyi + 1);
                    wvv[k] = max(wvv[k], prio);
                }
            }
            // unconditional centre-cell candidate (prio k=9)
            if (yc && x == gic) wvv[k] = max(wvv[k], base + 9);
            // gaussian: exp(-d2/4.5); beyond d2=300, value < e^-66 ~ 0 in f32
            float ddx = (float)x - tx;
            float d2 = ddx * ddx + ddy2;
            if (d2 <= 300.0f) gm[k] = fmaxf(gm[k], expf(-d2 / 4.5f));
        }
    }

    // ---- attention channel sum: 32 x float4 (16B/lane, fully coalesced) ----
    const float* sp = sal + (size_t)b * NCH * HW + hw0;
    float4 ss = make_float4(0.0f, 0.0f, 0.0f, 0.0f);
#pragma unroll
    for (int c = 0; c < NCH; ++c) {
        float4 v = *reinterpret_cast<const float4*>(sp + (size_t)c * HW);
        ss.x += v.x; ss.y += v.y; ss.z += v.z; ss.w += v.w;
    }

    // ---- raw: 4 cells * 7 floats = 28 floats = 7 aligned float4 loads ----
    float rr[28];
    const float4* rp = reinterpret_cast<const float4*>(raw + (size_t)p0 * 7);
#pragma unroll
    for (int q = 0; q < 7; ++q) reinterpret_cast<float4*>(rr)[q] = rp[q];

    float smv[4] = {ss.x, ss.y, ss.z, ss.w};

    float attn_t = 0.0f, conf_t = 0.0f, ciou_t = 0.0f, cls_t = 0.0f, posf = 0.0f;

#pragma unroll
    for (int k = 0; k < 4; ++k) {
        // attention MSE term
        float smean = smv[k] * (1.0f / 32.0f);
        float dm = smean - gm[k];
        attn_t += dm * dm;

        const float* r = rr + k * 7;
        float r0 = r[0], r1 = r[1], r2 = r[2], r3 = r[3];
        float z = r[4], l0 = r[5], l1 = r[6];

        float pcx = (sigmoidf_(r0) + (float)(xb + k)) / (float)FW;
        float pcy = (sigmoidf_(r1) + fy) / (float)FH;
        float pw = expf(fminf(fmaxf(r2, -4.0f), 4.0f)) / (float)FW;
        float ph = expf(fminf(fmaxf(r3, -4.0f), 4.0f)) / (float)FH;
        float conf = sigmoidf_(z);

        int wv = wvv[k];
        if (wv >= 0) {
            posf += 1.0f;
            float omc = 1.0f - conf;
            conf_t += 0.25f * omc * omc * softplusf_(-z);

            int t = wv / 10;
            float tcx = targets[t * 6 + 1], tcy = targets[t * 6 + 2];
            float tw = targets[t * 6 + 3], th = targets[t * 6 + 4];
            int cls = (int)targets[t * 6 + 5];

            // CIoU
            float px1 = pcx - pw * 0.5f, py1 = pcy - ph * 0.5f;
            float px2 = pcx + pw * 0.5f, py2 = pcy + ph * 0.5f;
            float tx1 = tcx - tw * 0.5f, ty1 = tcy - th * 0.5f;
            float tx2 = tcx + tw * 0.5f, ty2 = tcy + th * 0.5f;
            float iw = fmaxf(fminf(px2, tx2) - fmaxf(px1, tx1), 0.0f);
            float ih = fmaxf(fminf(py2, ty2) - fmaxf(py1, ty1), 0.0f);
            float inter = iw * ih;
            float uni = pw * ph + tw * th - inter;
            float iou = inter / (uni + EPS_);
            float cw = fmaxf(px2, tx2) - fminf(px1, tx1);
            float chh = fmaxf(py2, ty2) - fminf(py1, ty1);
            float c2 = cw * cw + chh * chh + EPS_;
            float dcx = pcx - tcx, dcy = pcy - tcy;
            float d2 = dcx * dcx + dcy * dcy;
            float dv = atanf(tw / (th + EPS_)) - atanf(pw / (ph + EPS_));
            float v = (4.0f / (float)(M_PI * M_PI)) * dv * dv;
            float alpha = v / (1.0f - iou + v + EPS_);
            ciou_t += 1.0f - iou + d2 / c2 + alpha * v;

            // class NLL (2 classes)
            float m_ = fmaxf(l0, l1);
            float lse = m_ + logf(expf(l0 - m_) + expf(l1 - m_));
            cls_t += lse - ((cls == 0) ? l0 : l1);
        } else {
            conf_t += 0.75f * conf * conf * softplusf_(z);
        }
    }

    // ---- block reduction of 5 sums ----
    float vals[5] = {attn_t, conf_t, ciou_t, cls_t, posf};
#pragma unroll
    for (int j = 0; j < 5; ++j) {
        float v = vals[j];
#pragma unroll
        for (int o = 32; o > 0; o >>= 1) v += __shfl_down(v, o, 64);
        vals[j] = v;
    }
    __shared__ float red[4][5];
    int lane = threadIdx.x & 63;
    int wid = threadIdx.x >> 6;
    if (lane == 0) {
#pragma unroll
        for (int j = 0; j < 5; ++j) red[wid][j] = vals[j];
    }
    __syncthreads();
    if (threadIdx.x == 0) {
#pragma unroll
        for (int j = 0; j < 5; ++j) {
            partials[blockIdx.x * 5 + j] = red[0][j] + red[1][j] + red[2][j] + red[3][j];
        }
    }
}

// ---------------- finalize: reduce partials, combine loss ----------------
__global__ __launch_bounds__(256) void finalize_kernel(const float* __restrict__ partials,
                                                       int nblk, float* __restrict__ out) {
    __shared__ double red[256][5];
    double acc[5] = {0, 0, 0, 0, 0};
    for (int i = threadIdx.x; i < nblk; i += 256) {
#pragma unroll
        for (int j = 0; j < 5; ++j) acc[j] += (double)partials[i * 5 + j];
    }
#pragma unroll
    for (int j = 0; j < 5; ++j) red[threadIdx.x][j] = acc[j];
    __syncthreads();
    for (int s = 128; s > 0; s >>= 1) {
        if (threadIdx.x < s) {
#pragma unroll
            for (int j = 0; j < 5; ++j) red[threadIdx.x][j] += red[threadIdx.x + s][j];
        }
        __syncthreads();
    }
    if (threadIdx.x == 0) {
        double attn = red[0][0];
        double conf = red[0][1];
        double ciou = red[0][2];
        double cls = red[0][3];
        double npos = red[0][4];
        double norm = fmax(npos, 1.0);
        double loss = 2.0 * ciou / norm + 1.0 * conf / norm + 1.0 * cls / norm +
                      5.0 * (attn / (double)(BATCH * HW));
        out[0] = (float)loss;
    }
}

extern "C" void kernel_launch(void* const* d_in, const int* in_sizes, int n_in,
                              void* d_out, int out_size, void* d_ws, size_t ws_size,
                              hipStream_t stream) {
    const float* raw = (const float*)d_in[0];      // (16, 65536, 7)
    const float* sal = (const float*)d_in[1];      // (16, 32, 256, 256)
    const float* targets = (const float*)d_in[2];  // (256, 6)
    float* out = (float*)d_out;

    float* partials = (float*)d_ws;                // 1024*5 floats

    const int NBLK4 = (BATCH * HW) / (256 * 4);    // 1024 blocks, 4 cells/thread

    main_kernel<<<NBLK4, 256, 0, stream>>>(raw, sal, targets, partials);
    finalize_kernel<<<1, 256, 0, stream>>>(partials, NBLK4, out);
}